// Round 1
// baseline (671.594 us; speedup 1.0000x reference)
//
#include <hip/hip_runtime.h>
#include <hip/hip_bf16.h>

typedef unsigned short ushortT;
typedef __attribute__((ext_vector_type(8))) short short8;
typedef __attribute__((ext_vector_type(4))) float f32x4;

#define CIN 512
#define COUTC 512
#define HIDC 512
#define BATCH 16
#define HDIM 64
#define WDIM 64
#define HP 66   // padded spatial

// ws layout (bytes):
//   s     @ 0        : 16*512*4   = 32768
//   d     @ 32768    : 16*512*4   = 32768
//   w2    @ 65536    : 512*512*4  = 1048576
//   wbt   @ 1114112  : 9*512*512*2 = 4718592   (bf16, tap-major [t][o][i])
//   xpad  @ 5832704  : 16*66*66*512*2 = 71368704 (bf16 NHWC, zero-padded)
// total ~77.2 MB

__device__ __forceinline__ unsigned short f2bf(float f) {
    __hip_bfloat16 h = __float2bfloat16(f);
    return __builtin_bit_cast(unsigned short, h);
}

__device__ __forceinline__ void gload16(const ushortT* g, ushortT* l) {
    __builtin_amdgcn_global_load_lds(
        (const __attribute__((address_space(1))) void*)g,
        (__attribute__((address_space(3))) void*)l, 16, 0, 0);
}

// s[b][i] = (y[b,:] . mod_w[i,:]) / sqrt(512) + mod_b[i] + 1
__global__ void k_style(const float* __restrict__ y, const float* __restrict__ mw,
                        const float* __restrict__ mb, float* __restrict__ s) {
    int t = blockIdx.x * 256 + threadIdx.x;   // 0..8191
    int b = t >> 9, i = t & 511;
    const float* yr = y + b * HIDC;
    const float* wr = mw + (size_t)i * HIDC;
    float acc = 0.f;
    #pragma unroll 4
    for (int h = 0; h < HIDC; h += 4) {
        acc += yr[h] * wr[h] + yr[h+1] * wr[h+1] + yr[h+2] * wr[h+2] + yr[h+3] * wr[h+3];
    }
    s[t] = acc * 0.04419417382415922f + mb[i] + 1.0f;
}

// wbt[k][o][i] = bf16(w[o][i][k] * coef);  w2[o][i] = sum_k (w*coef)^2
__global__ void k_prepw(const float* __restrict__ w, float* __restrict__ w2,
                        ushortT* __restrict__ wbt) {
    int t = blockIdx.x * 256 + threadIdx.x;   // 0..262143  (= o*512 + i)
    const float* wp = w + (size_t)t * 9;
    const float coef = 0.014731391274719739f; // 1/sqrt(4608)
    float sum = 0.f;
    #pragma unroll
    for (int k = 0; k < 9; ++k) {
        float v = wp[k] * coef;
        sum += v * v;
        wbt[(size_t)k * (COUTC * CIN) + t] = f2bf(v);
    }
    w2[t] = sum;
}

// d[b][o] = rsqrt(sum_i w2[o][i] * s[b][i]^2 + 1e-8)
__global__ void k_demod(const float* __restrict__ w2, const float* __restrict__ s,
                        float* __restrict__ d) {
    int t = blockIdx.x * 256 + threadIdx.x;   // 0..8191
    int b = t >> 9, o = t & 511;
    const float* sr = s + b * CIN;
    const float* wr = w2 + (size_t)o * CIN;
    float acc = 1e-8f;
    #pragma unroll 4
    for (int i = 0; i < CIN; ++i) {
        float sv = sr[i];
        acc += wr[i] * sv * sv;
    }
    d[t] = rsqrtf(acc);
}

// xpad[b][row][col][ch] = bf16(x[b][ch][row-1][col-1] * s[b][ch]), zero border.
// grid = B*66*16 blocks (16 ch-chunks of 32), 256 threads.
__global__ void k_pad(const float* __restrict__ x, const float* __restrict__ s,
                      ushortT* __restrict__ xpad) {
    __shared__ __align__(16) ushortT tile[64 * 32];
    int bid = blockIdx.x;
    int cchunk = bid & 15;
    int rem = bid >> 4;
    int prow = rem % HP;
    int b = rem / HP;
    int tid = threadIdx.x;
    size_t rowbase = (((size_t)b * HP + prow) * HP) * CIN + cchunk * 32;
    if (prow == 0 || prow == HP - 1) {
        short8 z = {};
        for (int q = tid; q < HP * 4; q += 256) {
            int col = q >> 2, sub = q & 3;
            *(short8*)(xpad + rowbase + (size_t)col * CIN + sub * 8) = z;
        }
        return;
    }
    int xr = prow - 1;
    int c = tid >> 3;             // 0..31 channel within chunk
    int w0 = (tid & 7) * 8;       // 8 pixels per thread
    const float* xp = x + (((size_t)b * CIN + cchunk * 32 + c) * HDIM + xr) * WDIM + w0;
    float sv = s[b * CIN + cchunk * 32 + c];
    #pragma unroll
    for (int j = 0; j < 8; ++j) {
        tile[(w0 + j) * 32 + c] = f2bf(xp[j] * sv);
    }
    __syncthreads();
    int col = 1 + (tid >> 2), sub = tid & 3;  // cols 1..64
    short8 v = *(const short8*)(tile + ((col - 1) * 32 + sub * 8));
    *(short8*)(xpad + rowbase + (size_t)col * CIN + sub * 8) = v;
    if (tid < 8) {
        short8 z = {};
        int bcol = (tid < 4) ? 0 : (HP - 1);
        *(short8*)(xpad + rowbase + (size_t)bcol * CIN + (tid & 3) * 8) = z;
    }
}

// Implicit-GEMM conv: tile 128 cout x 128 pos (2 rows x 64 cols of one image).
// K-loop: 9 taps x 16 chunks of 32 channels. m97 structure.
__global__ __launch_bounds__(256, 2) void k_conv(
    const ushortT* __restrict__ wbt, const ushortT* __restrict__ xpad,
    const float* __restrict__ dcoef, const float* __restrict__ bias,
    const float* __restrict__ noise, const float* __restrict__ nscp,
    float* __restrict__ out)
{
    __shared__ __align__(16) ushortT As[128 * 32];
    __shared__ __align__(16) ushortT Bs[128 * 32];

    int tid = threadIdx.x;
    int lane = tid & 63;
    int wave = tid >> 6;
    int wave_m = wave >> 1, wave_n = wave & 1;

    int bid = blockIdx.x;
    int mtile = bid >> 9;          // slow: all CUs share one 128-cout weight slab (L2-friendly)
    int ntile = bid & 511;
    int b = ntile >> 5;
    int h0 = (ntile & 31) << 1;
    int cout0 = mtile << 7;

    // staging chunk ids (16B per lane per call)
    int q0 = tid;            // chunk 0..255
    int q1 = 256 + tid;      // chunk 256..511
    size_t aoff0 = (size_t)(cout0 + (q0 >> 2)) * CIN + (q0 & 3) * 8;
    size_t aoff1 = (size_t)(cout0 + (q1 >> 2)) * CIN + (q1 & 3) * 8;
    int p0 = q0 >> 2, p1 = q1 >> 2;
    size_t boff0 = (((size_t)b * HP + h0 + (p0 >> 6)) * HP + (p0 & 63)) * CIN + (q0 & 3) * 8;
    size_t boff1 = (((size_t)b * HP + h0 + (p1 >> 6)) * HP + (p1 & 63)) * CIN + (q1 & 3) * 8;

    ushortT* AsW0 = As + wave * 512;            // lds dest bases (HW adds lane*16B)
    ushortT* AsW1 = As + 2048 + wave * 512;
    ushortT* BsW0 = Bs + wave * 512;
    ushortT* BsW1 = Bs + 2048 + wave * 512;

    int koff = (lane >> 4) * 8;
    int arow = wave_m * 64 + (lane & 15);
    int brow = wave_n * 64 + (lane & 15);

    f32x4 acc[4][4] = {};

    for (int t = 0; t < 9; ++t) {
        const ushortT* At0 = wbt + (size_t)t * (COUTC * CIN) + aoff0;
        const ushortT* At1 = wbt + (size_t)t * (COUTC * CIN) + aoff1;
        size_t tshift = ((size_t)(t / 3) * HP + (t % 3)) * CIN;
        const ushortT* Bt0 = xpad + boff0 + tshift;
        const ushortT* Bt1 = xpad + boff1 + tshift;
        for (int cc = 0; cc < 16; ++cc) {
            int co = cc * 32;
            gload16(At0 + co, AsW0);
            gload16(At1 + co, AsW1);
            gload16(Bt0 + co, BsW0);
            gload16(Bt1 + co, BsW1);
            __builtin_amdgcn_s_waitcnt(0);
            __syncthreads();
            short8 af[4], bf[4];
            #pragma unroll
            for (int mi = 0; mi < 4; ++mi)
                af[mi] = *(const short8*)(As + (arow + mi * 16) * 32 + koff);
            #pragma unroll
            for (int nj = 0; nj < 4; ++nj)
                bf[nj] = *(const short8*)(Bs + (brow + nj * 16) * 32 + koff);
            #pragma unroll
            for (int mi = 0; mi < 4; ++mi) {
                #pragma unroll
                for (int nj = 0; nj < 4; ++nj)
                    acc[mi][nj] = __builtin_amdgcn_mfma_f32_16x16x32_bf16(
                        af[mi], bf[nj], acc[mi][nj], 0, 0, 0);
            }
            __syncthreads();
        }
    }

    // epilogue: out = acc * d[b,o] + noise*nscale + bias
    float ns = nscp[0];
    int col = lane & 15, rq = lane >> 4;
    #pragma unroll
    for (int nj = 0; nj < 4; ++nj) {
        int pos = wave_n * 64 + nj * 16 + col;
        int hh = h0 + (pos >> 6), ww = pos & 63;
        float nz = noise[((size_t)b << 12) + (hh << 6) + ww] * ns;
        #pragma unroll
        for (int mi = 0; mi < 4; ++mi) {
            int coutb = cout0 + wave_m * 64 + mi * 16 + rq * 4;
            f32x4 dv = *(const f32x4*)(dcoef + b * COUTC + coutb);
            f32x4 bv = *(const f32x4*)(bias + coutb);
            f32x4 a = acc[mi][nj];
            #pragma unroll
            for (int r = 0; r < 4; ++r) {
                out[(((size_t)(b * COUTC + coutb + r)) << 12) + (hh << 6) + ww]
                    = a[r] * dv[r] + nz + bv[r];
            }
        }
    }
}

extern "C" void kernel_launch(void* const* d_in, const int* in_sizes, int n_in,
                              void* d_out, int out_size, void* d_ws, size_t ws_size,
                              hipStream_t stream) {
    const float* x      = (const float*)d_in[0];
    const float* y      = (const float*)d_in[1];
    const float* noise  = (const float*)d_in[2];
    const float* weight = (const float*)d_in[3];
    const float* bias   = (const float*)d_in[4];
    const float* mod_w  = (const float*)d_in[5];
    const float* mod_b  = (const float*)d_in[6];
    const float* nsc    = (const float*)d_in[7];
    float* out = (float*)d_out;

    char* ws = (char*)d_ws;
    float*   s     = (float*)(ws);
    float*   dcoef = (float*)(ws + 32768);
    float*   w2    = (float*)(ws + 65536);
    ushortT* wbt   = (ushortT*)(ws + 1114112);
    ushortT* xpad  = (ushortT*)(ws + 5832704);

    k_style<<<dim3(32), dim3(256), 0, stream>>>(y, mod_w, mod_b, s);
    k_prepw<<<dim3(1024), dim3(256), 0, stream>>>(weight, w2, wbt);
    k_demod<<<dim3(32), dim3(256), 0, stream>>>(w2, s, dcoef);
    k_pad<<<dim3(BATCH * HP * 16), dim3(256), 0, stream>>>(x, s, xpad);
    k_conv<<<dim3(2048), dim3(256), 0, stream>>>(wbt, xpad, dcoef, bias, noise, nsc, out);
}

// Round 2
// 582.959 us; speedup vs baseline: 1.1520x; 1.1520x over previous
//
#include <hip/hip_runtime.h>
#include <hip/hip_bf16.h>

typedef unsigned short ushortT;
typedef __attribute__((ext_vector_type(8))) short short8;
typedef __attribute__((ext_vector_type(4))) float f32x4;

#define CIN 512
#define COUTC 512
#define HIDC 512
#define BATCH 16
#define HDIM 64
#define WDIM 64
#define HP 66   // padded spatial

// ws layout (bytes):
//   s     @ 0        : 16*512*4   = 32768
//   d     @ 32768    : 16*512*4   = 32768
//   w2    @ 65536    : 512*512*4  = 1048576
//   wbt   @ 1114112  : 9*512*512*2 = 4718592   (bf16, tap-major [t][o][i])
//   xpad  @ 5832704  : 16*66*66*512*2 = 71368704 (bf16 NHWC, zero-padded)

__device__ __forceinline__ unsigned short f2bf(float f) {
    __hip_bfloat16 h = __float2bfloat16(f);
    return __builtin_bit_cast(unsigned short, h);
}

__device__ __forceinline__ void gload16(const ushortT* g, ushortT* l) {
    __builtin_amdgcn_global_load_lds(
        (const __attribute__((address_space(1))) void*)g,
        (__attribute__((address_space(3))) void*)l, 16, 0, 0);
}

// s[b][i] = (y[b,:] . mod_w[i,:]) / sqrt(512) + mod_b[i] + 1   — one wave per (b,i)
__global__ void k_style(const float* __restrict__ y, const float* __restrict__ mw,
                        const float* __restrict__ mb, float* __restrict__ s) {
    int lane = threadIdx.x & 63;
    int wid = blockIdx.x * 4 + (threadIdx.x >> 6);   // 0..8191
    int b = wid >> 9, i = wid & 511;
    int h0 = lane * 8;
    float4 ya = *(const float4*)(y + b * HIDC + h0);
    float4 yb = *(const float4*)(y + b * HIDC + h0 + 4);
    float4 wa = *(const float4*)(mw + (size_t)i * HIDC + h0);
    float4 wb = *(const float4*)(mw + (size_t)i * HIDC + h0 + 4);
    float v = ya.x*wa.x + ya.y*wa.y + ya.z*wa.z + ya.w*wa.w
            + yb.x*wb.x + yb.y*wb.y + yb.z*wb.z + yb.w*wb.w;
    #pragma unroll
    for (int off = 32; off > 0; off >>= 1) v += __shfl_down(v, off);
    if (lane == 0) s[wid] = v * 0.04419417382415922f + mb[i] + 1.0f;
}

// wbt[k][o][i] = bf16(w[o][i][k] * coef);  w2[o][i] = sum_k (w*coef)^2
__global__ void k_prepw(const float* __restrict__ w, float* __restrict__ w2,
                        ushortT* __restrict__ wbt) {
    int t = blockIdx.x * 256 + threadIdx.x;   // o*512 + i
    const float* wp = w + (size_t)t * 9;
    const float coef = 0.014731391274719739f; // 1/sqrt(4608)
    float sum = 0.f;
    #pragma unroll
    for (int k = 0; k < 9; ++k) {
        float v = wp[k] * coef;
        sum += v * v;
        wbt[(size_t)k * (COUTC * CIN) + t] = f2bf(v);
    }
    w2[t] = sum;
}

// d[b][o] = rsqrt(sum_i w2[o][i] * s[b][i]^2 + 1e-8)  — one wave per (b,o)
__global__ void k_demod(const float* __restrict__ w2, const float* __restrict__ s,
                        float* __restrict__ d) {
    int lane = threadIdx.x & 63;
    int wid = blockIdx.x * 4 + (threadIdx.x >> 6);   // 0..8191
    int b = wid >> 9, o = wid & 511;
    int i0 = lane * 8;
    float4 wa = *(const float4*)(w2 + (size_t)o * CIN + i0);
    float4 wb = *(const float4*)(w2 + (size_t)o * CIN + i0 + 4);
    float4 sa = *(const float4*)(s + b * CIN + i0);
    float4 sb = *(const float4*)(s + b * CIN + i0 + 4);
    float v = wa.x*sa.x*sa.x + wa.y*sa.y*sa.y + wa.z*sa.z*sa.z + wa.w*sa.w*sa.w
            + wb.x*sb.x*sb.x + wb.y*sb.y*sb.y + wb.z*sb.z*sb.z + wb.w*sb.w*sb.w;
    #pragma unroll
    for (int off = 32; off > 0; off >>= 1) v += __shfl_down(v, off);
    if (lane == 0) d[wid] = rsqrtf(v + 1e-8f);
}

// xpad[b][row][col][ch] = bf16(x[b][ch][row-1][col-1] * s[b][ch]), zero border.
// fp32 LDS tile, stride 33 (odd) => scalar LDS writes/reads conflict-free.
__global__ void k_pad(const float* __restrict__ x, const float* __restrict__ s,
                      ushortT* __restrict__ xpad) {
    __shared__ float tilef[64 * 33];
    int bid = blockIdx.x;
    int cchunk = bid & 15;
    int rem = bid >> 4;
    int prow = rem % HP;
    int b = rem / HP;
    int tid = threadIdx.x;
    size_t rowbase = (((size_t)b * HP + prow) * HP) * CIN + cchunk * 32;
    if (prow == 0 || prow == HP - 1) {
        short8 z = {};
        for (int q = tid; q < HP * 4; q += 256) {
            int col = q >> 2, sub = q & 3;
            *(short8*)(xpad + rowbase + (size_t)col * CIN + sub * 8) = z;
        }
        return;
    }
    int xr = prow - 1;
    int u = tid & 15;          // 16 float4 segments along W
    #pragma unroll
    for (int cl = 0; cl < 32; cl += 16) {
        int c = cl + (tid >> 4);
        float4 v = *(const float4*)(x + (((size_t)b * CIN + cchunk * 32 + c) * HDIM + xr) * WDIM + u * 4);
        float sv = s[b * CIN + cchunk * 32 + c];
        tilef[(u * 4 + 0) * 33 + c] = v.x * sv;
        tilef[(u * 4 + 1) * 33 + c] = v.y * sv;
        tilef[(u * 4 + 2) * 33 + c] = v.z * sv;
        tilef[(u * 4 + 3) * 33 + c] = v.w * sv;
    }
    __syncthreads();
    int col = 1 + (tid >> 2), sub = tid & 3;  // cols 1..64
    const float* tr = tilef + (col - 1) * 33 + sub * 8;
    short8 o;
    #pragma unroll
    for (int r = 0; r < 8; ++r) o[r] = (short)f2bf(tr[r]);
    *(short8*)(xpad + rowbase + (size_t)col * CIN + sub * 8) = o;
    if (tid < 8) {
        short8 z = {};
        int bcol = (tid < 4) ? 0 : (HP - 1);
        *(short8*)(xpad + rowbase + (size_t)bcol * CIN + (tid & 3) * 8) = z;
    }
}

// Implicit-GEMM conv: tile 128 cout x 128 pos (2 rows x 64 cols of one image).
// BK=64 (9 taps x 8 chunks), XOR-swizzled LDS: chunk (row,sub) at slot sub^(row&7).
__global__ __launch_bounds__(256, 2) void k_conv(
    const ushortT* __restrict__ wbt, const ushortT* __restrict__ xpad,
    const float* __restrict__ dcoef, const float* __restrict__ bias,
    const float* __restrict__ noise, const float* __restrict__ nscp,
    float* __restrict__ out)
{
    __shared__ __align__(16) ushortT As[128 * 64];
    __shared__ __align__(16) ushortT Bs[128 * 64];

    int tid = threadIdx.x;
    int lane = tid & 63;
    int wave = tid >> 6;
    int wave_m = wave >> 1, wave_n = wave & 1;

    int bid = blockIdx.x;
    int mtile = bid >> 9;          // consecutive blocks share one 128-cout weight slab
    int ntile = bid & 511;
    int b = ntile >> 5;
    int h0 = (ntile & 31) << 1;
    int cout0 = mtile << 7;

    // staging: 1024 chunks of 16B per array, 4 calls x 256 threads.
    // chunk id a: LDS row=a>>3, slot=a&7; holds global sub = slot ^ (row&7).
    size_t asrc[4], bsrc[4];
    #pragma unroll
    for (int call = 0; call < 4; ++call) {
        int a = call * 256 + wave * 64 + lane;
        int row = a >> 3;
        int sub = (a & 7) ^ (row & 7);
        asrc[call] = (size_t)(cout0 + row) * CIN + sub * 8;
        int pr = h0 + (row >> 6);
        int pc = row & 63;
        bsrc[call] = ((size_t)(b * HP + pr) * HP + pc) * CIN + sub * 8;
    }
    ushortT* AsD[4]; ushortT* BsD[4];
    #pragma unroll
    for (int call = 0; call < 4; ++call) {
        AsD[call] = As + call * 2048 + wave * 512;
        BsD[call] = Bs + call * 2048 + wave * 512;
    }

    int l7 = lane & 7;
    int quad = lane >> 4;
    int arow = wave_m * 64 + (lane & 15);
    int brow = wave_n * 64 + (lane & 15);

    f32x4 acc[4][4] = {};

    for (int t = 0; t < 9; ++t) {
        const ushortT* At = wbt + (size_t)t * (COUTC * CIN);
        const ushortT* Bt = xpad + ((size_t)(t / 3) * HP + (t % 3)) * CIN;
        for (int cc = 0; cc < 8; ++cc) {
            int co = cc * 64;
            #pragma unroll
            for (int call = 0; call < 4; ++call) {
                gload16(At + asrc[call] + co, AsD[call]);
                gload16(Bt + bsrc[call] + co, BsD[call]);
            }
            __builtin_amdgcn_s_waitcnt(0);
            __syncthreads();
            #pragma unroll
            for (int kk = 0; kk < 2; ++kk) {
                int slot = ((kk * 4 + quad) ^ l7) * 8;
                short8 af[4], bf[4];
                #pragma unroll
                for (int mi = 0; mi < 4; ++mi)
                    af[mi] = *(const short8*)(As + (arow + mi * 16) * 64 + ((( kk*4+quad) ^ ((arow + mi*16) & 7)) * 8));
                #pragma unroll
                for (int nj = 0; nj < 4; ++nj)
                    bf[nj] = *(const short8*)(Bs + (brow + nj * 16) * 64 + (((kk*4+quad) ^ ((brow + nj*16) & 7)) * 8));
                (void)slot;
                #pragma unroll
                for (int mi = 0; mi < 4; ++mi) {
                    #pragma unroll
                    for (int nj = 0; nj < 4; ++nj)
                        acc[mi][nj] = __builtin_amdgcn_mfma_f32_16x16x32_bf16(
                            af[mi], bf[nj], acc[mi][nj], 0, 0, 0);
                }
            }
            __syncthreads();
        }
    }

    // epilogue: out = acc * d[b,o] + noise*nscale + bias
    float ns = nscp[0];
    int col = lane & 15, rq = lane >> 4;
    #pragma unroll
    for (int nj = 0; nj < 4; ++nj) {
        int pos = wave_n * 64 + nj * 16 + col;
        int hh = h0 + (pos >> 6), ww = pos & 63;
        float nz = noise[((size_t)b << 12) + (hh << 6) + ww] * ns;
        #pragma unroll
        for (int mi = 0; mi < 4; ++mi) {
            int coutb = cout0 + wave_m * 64 + mi * 16 + rq * 4;
            f32x4 dv = *(const f32x4*)(dcoef + b * COUTC + coutb);
            f32x4 bv = *(const f32x4*)(bias + coutb);
            f32x4 a = acc[mi][nj];
            #pragma unroll
            for (int r = 0; r < 4; ++r) {
                out[(((size_t)(b * COUTC + coutb + r)) << 12) + (hh << 6) + ww]
                    = a[r] * dv[r] + nz + bv[r];
            }
        }
    }
}

extern "C" void kernel_launch(void* const* d_in, const int* in_sizes, int n_in,
                              void* d_out, int out_size, void* d_ws, size_t ws_size,
                              hipStream_t stream) {
    const float* x      = (const float*)d_in[0];
    const float* y      = (const float*)d_in[1];
    const float* noise  = (const float*)d_in[2];
    const float* weight = (const float*)d_in[3];
    const float* bias   = (const float*)d_in[4];
    const float* mod_w  = (const float*)d_in[5];
    const float* mod_b  = (const float*)d_in[6];
    const float* nsc    = (const float*)d_in[7];
    float* out = (float*)d_out;

    char* ws = (char*)d_ws;
    float*   s     = (float*)(ws);
    float*   dcoef = (float*)(ws + 32768);
    float*   w2    = (float*)(ws + 65536);
    ushortT* wbt   = (ushortT*)(ws + 1114112);
    ushortT* xpad  = (ushortT*)(ws + 5832704);

    k_style<<<dim3(2048), dim3(256), 0, stream>>>(y, mod_w, mod_b, s);
    k_prepw<<<dim3(1024), dim3(256), 0, stream>>>(weight, w2, wbt);
    k_demod<<<dim3(2048), dim3(256), 0, stream>>>(w2, s, dcoef);
    k_pad<<<dim3(BATCH * HP * 16), dim3(256), 0, stream>>>(x, s, xpad);
    k_conv<<<dim3(2048), dim3(256), 0, stream>>>(wbt, xpad, dcoef, bias, noise, nsc, out);
}